// Round 1
// 219.856 us; speedup vs baseline: 1.3055x; 1.3055x over previous
//
#include <hip/hip_runtime.h>
#include <hip/hip_bf16.h>

#define D_DIM 768
#define B_DIM 8192
#define NCHUNK 32
#define BM 256
#define BN 256

typedef __attribute__((ext_vector_type(8))) short short8;
typedef __attribute__((ext_vector_type(4))) float f32x4;
typedef __attribute__((ext_vector_type(4))) unsigned short ushort4v;

// ws layout (bytes)
#define WS_XB   0                               // bf16[8192*768] = 12,582,912
#define WS_SQ   12582912                        // float[8192]    = 32,768
#define WS_CAND 12615680                        // float[8192*32*8] = 8,388,608
#define WS_ACC  21004288                        // float[1]

__device__ __forceinline__ void gl_lds16(const void* g, void* lds) {
  __builtin_amdgcn_global_load_lds(
      (const __attribute__((address_space(1))) unsigned int*)g,
      (__attribute__((address_space(3))) unsigned int*)lds, 16, 0, 0);
}

// branchless: maintain v[0..5] = six smallest seen, sorted ascending.
// (divergent-if version never whole-wave-skips in practice; exec juggling cost > body)
__device__ __forceinline__ void ins6(float c, float* v) {
  v[5] = fminf(v[5], c);
#pragma unroll
  for (int s = 5; s > 0; --s) {
    float lo = fminf(v[s - 1], v[s]);
    float hi = fmaxf(v[s - 1], v[s]);
    v[s - 1] = lo;
    v[s] = hi;
  }
}

// kernel 1: cast fp32 -> bf16 (vectorized), row sum-of-squares of bf16 values.
__global__ __launch_bounds__(256) void cast_sq_kernel(
    const float* __restrict__ x, unsigned short* __restrict__ xb,
    float* __restrict__ sq, float* __restrict__ acc) {
  const int t = threadIdx.x;
  const int w = t >> 6, lane = t & 63;
  const int row = blockIdx.x * 4 + w;
  if (blockIdx.x == 0 && t == 0) acc[0] = 0.0f;
  const f32x4* xr = (const f32x4*)(x + (size_t)row * D_DIM);
  ushort4v* xbr = (ushort4v*)(xb + (size_t)row * D_DIM);
  float s = 0.0f;
#pragma unroll
  for (int c = 0; c < 3; ++c) {
    const int idx = c * 64 + lane;
    f32x4 v = xr[idx];
    ushort4v u;
#pragma unroll
    for (int e = 0; e < 4; ++e) {
      __hip_bfloat16 h = __float2bfloat16(v[e]);
      unsigned short us;
      __builtin_memcpy(&us, &h, 2);
      u[e] = us;
      float vb = __bfloat162float(h);
      s += vb * vb;
    }
    xbr[idx] = u;
  }
#pragma unroll
  for (int off = 32; off > 0; off >>= 1) s += __shfl_down(s, off, 64);
  if (lane == 0) sq[row] = s;
}

// ---------------- kernel 2: 256x256 pipelined MFMA Gram + fused top-6 ----------------
// LDS: 2 dbuf x {A[2 K-halves][256][32], B[2 K-halves][256][32]} bf16 = 128 KiB.
// Seg swizzle within a K-half row (4 segs of 8 bf16): lds_seg = g_seg ^ ((R>>1)&3)
//   -> frag ds_read_b128: 8 lanes per 16B bank-slot, conflict-free.
// Schedule per K-tile (2 barriers, counted vmcnt, never 0 until tail):
//   [vmcnt(8); bar; stage(kt+1 K-half1); ds(kk0)+32 MFMA;
//    vmcnt(8); bar; stage(kt+2 K-half0 -> just-freed same-buffer region); ds(kk1)+32 MFMA]
#define AREG(b, kk) ((b) * 65536 + (kk) * 16384)
#define BREG(b, kk) ((b) * 65536 + 32768 + (kk) * 16384)
#define VMW(N) asm volatile("s_waitcnt vmcnt(" #N ")" ::: "memory")
#define BAR()                         \
  {                                   \
    asm volatile("" ::: "memory");    \
    __builtin_amdgcn_s_barrier();     \
    asm volatile("" ::: "memory");    \
  }

__global__ __launch_bounds__(512) void knn_gemm_kernel(
    const unsigned short* __restrict__ xb, const float* __restrict__ sq,
    float* __restrict__ cand) {
  __shared__ __align__(16) char smem[131072];
  const int t = threadIdx.x;
  const int lane = t & 63, w = t >> 6;
  const int wm = w >> 2, wn = w & 3;  // 2(M) x 4(N) wave grid; wave tile 128x64
  const int quad = lane >> 4, m16 = lane & 15;

  // XCD-aware bijective swizzle (nwg=1024 % 8 == 0)
  const int bid = blockIdx.y * gridDim.x + blockIdx.x;
  const int swz = (bid & 7) * 128 + (bid >> 3);
  const int rowBase = (swz & 31) * BM;
  const int chunk = swz >> 5;
  const int colBase = chunk * BN;

  // staging: thread t covers LDS row R0=t>>2 (and R0+128 on 2nd issue), lds seg t&3
  const int R0 = t >> 2;
  const int sg = (t & 3) ^ ((t >> 3) & 3);  // inverse swizzle on the global source
  const unsigned short* pA = xb + (size_t)(rowBase + R0) * D_DIM + sg * 8;
  const unsigned short* pB = xb + (size_t)(colBase + R0) * D_DIM + sg * 8;

  // fragment read bases: byte = R*64 + (quad ^ ((R>>1)&3))*16 ; (R>>1)&3 == (m16>>1)&3
  const int laneOff = ((quad ^ ((m16 >> 1) & 3)) << 4) + m16 * 64;
  const int aOff = wm * 8192 + laneOff;
  const int bOff = wn * 4096 + laneOff;

  float csq[4];
#pragma unroll
  for (int j = 0; j < 4; ++j) csq[j] = sq[colBase + wn * 64 + j * 16 + m16];

  f32x4 acc[8][4];
  const f32x4 zero = {0.0f, 0.0f, 0.0f, 0.0f};
#pragma unroll
  for (int i = 0; i < 8; ++i)
#pragma unroll
    for (int j = 0; j < 4; ++j) acc[i][j] = zero;

#define STAGE(P, EOFF, REGION)                                         \
  {                                                                    \
    gl_lds16((P) + (EOFF), smem + (REGION) + t * 16);                  \
    gl_lds16((P) + (EOFF) + 98304, smem + (REGION) + 8192 + t * 16);   \
  }

  short8 aF[4], bF[4];
#define LDA(BASE)                                                            \
  {                                                                          \
    _Pragma("unroll") for (int ii = 0; ii < 4; ++ii)                         \
        aF[ii] = *(const short8*)(smem + (BASE) + ii * 1024 + aOff);         \
  }
#define LDB(BASE)                                                            \
  {                                                                          \
    _Pragma("unroll") for (int j = 0; j < 4; ++j)                            \
        bF[j] = *(const short8*)(smem + (BASE) + j * 1024 + bOff);           \
  }
#define MFMAH(MH)                                                            \
  {                                                                          \
    __builtin_amdgcn_s_setprio(1);                                           \
    _Pragma("unroll") for (int ii = 0; ii < 4; ++ii)                         \
        _Pragma("unroll") for (int j = 0; j < 4; ++j)                        \
            acc[(MH) * 4 + ii][j] =                                          \
                __builtin_amdgcn_mfma_f32_16x16x32_bf16(                     \
                    aF[ii], bF[j], acc[(MH) * 4 + ii][j], 0, 0, 0);          \
    __builtin_amdgcn_s_setprio(0);                                           \
  }

  // prologue: k0{A0,B0,A1,B1}, k1{A0,B0} = 12 gl_lds in flight
  STAGE(pA, 0, AREG(0, 0));
  STAGE(pB, 0, BREG(0, 0));
  STAGE(pA, 32, AREG(0, 1));
  STAGE(pB, 32, BREG(0, 1));
  STAGE(pA, 64, AREG(1, 0));
  STAGE(pB, 64, BREG(1, 0));

#define KTILE(B, KT, S1, S2, VMA, VMB)                                 \
  {                                                                    \
    VMW(VMA);                                                          \
    BAR();                                                             \
    if (S1) STAGE(pA, ((KT) + 1) * 64 + 32, AREG((B) ^ 1, 1));         \
    LDA(AREG(B, 0));                                                   \
    LDB(BREG(B, 0));                                                   \
    MFMAH(0);                                                          \
    if (S1) STAGE(pB, ((KT) + 1) * 64 + 32, BREG((B) ^ 1, 1));         \
    LDA(AREG(B, 0) + 4096);                                            \
    MFMAH(1);                                                          \
    VMW(VMB);                                                          \
    BAR();                                                             \
    if (S2) STAGE(pA, ((KT) + 2) * 64, AREG(B, 0));                    \
    LDA(AREG(B, 1));                                                   \
    LDB(BREG(B, 1));                                                   \
    MFMAH(0);                                                          \
    if (S2) STAGE(pB, ((KT) + 2) * 64, BREG(B, 0));                    \
    LDA(AREG(B, 1) + 4096);                                            \
    MFMAH(1);                                                          \
  }

  for (int kt = 0; kt < 10; kt += 2) {
    KTILE(0, kt, 1, 1, 8, 8);
    KTILE(1, kt + 1, 1, 1, 8, 8);
  }
  KTILE(0, 10, 1, 0, 8, 8);
  KTILE(1, 11, 0, 0, 4, 0);

  // ---------------- epilogue: 4 groups of 64 rows ----------------
  // selection key = csq[col] - 2*G (row-constant rsq added after: order-invariant)
  float* distS = (float*)smem;  // [64][260] f32, reuses staging LDS
#pragma unroll
  for (int g = 0; g < 4; ++g) {
    BAR();
    if (wm == (g >> 1)) {
      const int ih = (g & 1) * 4;
#pragma unroll
      for (int ii = 0; ii < 4; ++ii)
#pragma unroll
        for (int j = 0; j < 4; ++j)
#pragma unroll
          for (int r = 0; r < 4; ++r)
            distS[(ii * 16 + quad * 4 + r) * 260 + wn * 64 + j * 16 + m16] =
                csq[j] - 2.0f * acc[ih + ii][j][r];
    }
    BAR();
    // select: 8 threads/row x 32 cols, per-seg rotated start -> conflict-free banks
    const int r_l = t >> 3, s = t & 7;
    const float* drow = distS + r_l * 260 + s * 32;
    float v[6];
#pragma unroll
    for (int q = 0; q < 6; ++q) v[q] = 1e30f;
#pragma unroll
    for (int k = 0; k < 8; ++k) {
      f32x4 dv = *(const f32x4*)(drow + ((k + s) & 7) * 4);
      ins6(dv[0], v);
      ins6(dv[1], v);
      ins6(dv[2], v);
      ins6(dv[3], v);
    }
    // in-wave butterfly merge across the 8 segment-threads of each row
#pragma unroll
    for (int st = 1; st <= 4; st <<= 1) {
      float o[6];
#pragma unroll
      for (int q = 0; q < 6; ++q) o[q] = __shfl_xor(v[q], st, 64);
#pragma unroll
      for (int q = 0; q < 6; ++q) ins6(o[q], v);
    }
    if (s == 0) {
      const int grow = rowBase + g * 64 + r_l;
      const float rsq = sq[grow];
      float* o = cand + ((size_t)grow * NCHUNK + chunk) * 8;
#pragma unroll
      for (int q = 0; q < 6; ++q) o[q] = fmaxf(v[q] + rsq, 0.0f);
    }
  }
}

// kernel 3: per-row merge of chunk candidates (d^2) -> sqrt -> log -> global sum
__global__ __launch_bounds__(256) void knn_merge_kernel(
    const float* __restrict__ cand, float* __restrict__ acc) {
  const int r = blockIdx.x * 256 + threadIdx.x;
  const float* cr = cand + (size_t)r * (NCHUNK * 8);
  float v[6];
#pragma unroll
  for (int s = 0; s < 6; ++s) v[s] = 1e30f;
  for (int c = 0; c < NCHUNK; ++c) {
#pragma unroll
    for (int s = 0; s < 6; ++s) ins6(cr[c * 8 + s], v);
  }
  // v sorted ascending on d^2: v[0] = self (~0); knn_mean = mean of sqrt(v[1..5])
  const float mean =
      (sqrtf(v[1]) + sqrtf(v[2]) + sqrtf(v[3]) + sqrtf(v[4]) + sqrtf(v[5])) * 0.2f;
  float term = logf(mean + 1e-8f);
#pragma unroll
  for (int off = 32; off > 0; off >>= 1) term += __shfl_down(term, off, 64);
  __shared__ float red[4];
  if ((threadIdx.x & 63) == 0) red[threadIdx.x >> 6] = term;
  __syncthreads();
  if (threadIdx.x == 0) atomicAdd(acc, red[0] + red[1] + red[2] + red[3]);
}

__global__ void finalize_kernel(const float* __restrict__ acc, float* __restrict__ out) {
  out[0] = -acc[0] * (1.0f / 8192.0f);
}

extern "C" void kernel_launch(void* const* d_in, const int* in_sizes, int n_in,
                              void* d_out, int out_size, void* d_ws, size_t ws_size,
                              hipStream_t stream) {
  const float* x = (const float*)d_in[0];
  float* out = (float*)d_out;
  char* ws = (char*)d_ws;
  unsigned short* xb = (unsigned short*)(ws + WS_XB);
  float* sq = (float*)(ws + WS_SQ);
  float* cand = (float*)(ws + WS_CAND);
  float* acc = (float*)(ws + WS_ACC);

  cast_sq_kernel<<<B_DIM / 4, 256, 0, stream>>>(x, xb, sq, acc);
  knn_gemm_kernel<<<dim3(B_DIM / BM, B_DIM / BN), 512, 0, stream>>>(xb, sq, cand);
  knn_merge_kernel<<<B_DIM / 256, 256, 0, stream>>>(cand, acc);
  finalize_kernel<<<1, 1, 0, stream>>>(acc, out);
}

// Round 2
// 205.996 us; speedup vs baseline: 1.3933x; 1.0673x over previous
//
#include <hip/hip_runtime.h>
#include <hip/hip_bf16.h>

#define D_DIM 768
#define B_DIM 8192
#define NCHUNK 32
#define BM 256
#define BN 256

typedef __attribute__((ext_vector_type(8))) short short8;
typedef __attribute__((ext_vector_type(4))) float f32x4;
typedef __attribute__((ext_vector_type(4))) unsigned short ushort4v;

// ws layout (bytes)
#define WS_XB   0                               // bf16[8192*768] = 12,582,912
#define WS_SQ   12582912                        // float[8192]    = 32,768
#define WS_CAND 12615680                        // float[8192*32*8] = 8,388,608
#define WS_ACC  21004288                        // float[1]

__device__ __forceinline__ void gl_lds16(const void* g, void* lds) {
  __builtin_amdgcn_global_load_lds(
      (const __attribute__((address_space(1))) unsigned int*)g,
      (__attribute__((address_space(3))) unsigned int*)lds, 16, 0, 0);
}

// branchless: maintain v[0..5] = six smallest seen, sorted ascending.
__device__ __forceinline__ void ins6(float c, float* v) {
  v[5] = fminf(v[5], c);
#pragma unroll
  for (int s = 5; s > 0; --s) {
    float lo = fminf(v[s - 1], v[s]);
    float hi = fmaxf(v[s - 1], v[s]);
    v[s - 1] = lo;
    v[s] = hi;
  }
}

// kernel 1: cast fp32 -> bf16 (vectorized), row sum-of-squares of bf16 values.
__global__ __launch_bounds__(256) void cast_sq_kernel(
    const float* __restrict__ x, unsigned short* __restrict__ xb,
    float* __restrict__ sq, float* __restrict__ acc) {
  const int t = threadIdx.x;
  const int w = t >> 6, lane = t & 63;
  const int row = blockIdx.x * 4 + w;
  if (blockIdx.x == 0 && t == 0) acc[0] = 0.0f;
  const f32x4* xr = (const f32x4*)(x + (size_t)row * D_DIM);
  ushort4v* xbr = (ushort4v*)(xb + (size_t)row * D_DIM);
  float s = 0.0f;
#pragma unroll
  for (int c = 0; c < 3; ++c) {
    const int idx = c * 64 + lane;
    f32x4 v = xr[idx];
    ushort4v u;
#pragma unroll
    for (int e = 0; e < 4; ++e) {
      __hip_bfloat16 h = __float2bfloat16(v[e]);
      unsigned short us;
      __builtin_memcpy(&us, &h, 2);
      u[e] = us;
      float vb = __bfloat162float(h);
      s += vb * vb;
    }
    xbr[idx] = u;
  }
#pragma unroll
  for (int off = 32; off > 0; off >>= 1) s += __shfl_down(s, off, 64);
  if (lane == 0) sq[row] = s;
}

// ---------------- kernel 2: 256x256, 4-phase-per-K-tile MFMA Gram + fused top-6 -----
// LDS: 2 dbuf x {A[2 kh][256][32], B[2 kh][256][32]} bf16 = 128 KiB.
// Seg swizzle (lds_seg = g_seg ^ ((R>>1)&3)) -> conflict-free ds_read_b128 frags.
// Phase = { ds_read subtile ; stage 1 unit (2 gl_lds) ; [vmcnt(4) at P2/P4] ;
//           barrier ; lgkmcnt(0) ; setprio(1) 16 MFMA setprio(0) ; barrier }
// Steady state: 8 gl_lds in flight, vmcnt(4) releases exactly the 2 units the
// next phases read; vmcnt(0) only in the last K-tile.
#define AREG(b, kk) ((b) * 65536 + (kk) * 16384)
#define BREG(b, kk) ((b) * 65536 + 32768 + (kk) * 16384)
#define VMW(N) asm volatile("s_waitcnt vmcnt(" #N ")" ::: "memory")
#define LGKM0() asm volatile("s_waitcnt lgkmcnt(0)" ::: "memory")
#define BAR()                         \
  {                                   \
    asm volatile("" ::: "memory");    \
    __builtin_amdgcn_s_barrier();     \
    asm volatile("" ::: "memory");    \
  }

__global__ __launch_bounds__(512) void knn_gemm_kernel(
    const unsigned short* __restrict__ xb, const float* __restrict__ sq,
    float* __restrict__ cand) {
  __shared__ __align__(16) char smem[131072];
  const int t = threadIdx.x;
  const int lane = t & 63, w = t >> 6;
  const int wm = w >> 2, wn = w & 3;  // 2(M) x 4(N) wave grid; wave tile 128x64
  const int quad = lane >> 4, m16 = lane & 15;

  // XCD-aware remap: XCD x owns chunks 4x..4x+3; its 32 concurrent blocks cover
  // 8 row-tiles x 4 chunks (4.7 MB footprint vs 12.6 MB column-major).
  const int bid = blockIdx.y * gridDim.x + blockIdx.x;  // 0..1023
  const int xcd = bid & 7, l = bid >> 3;                // l in 0..127
  const int chunk = xcd * 4 + ((l >> 3) & 3);
  const int rowBase = ((l & 7) + ((l >> 5) << 3)) * BM;
  const int colBase = chunk * BN;

  // staging: thread t covers LDS row R0=t>>2 (and R0+128 on 2nd issue), lds seg t&3
  const int R0 = t >> 2;
  const int sg = (t & 3) ^ ((t >> 3) & 3);  // inverse swizzle on the global source
  const unsigned short* pA = xb + (size_t)(rowBase + R0) * D_DIM + sg * 8;
  const unsigned short* pB = xb + (size_t)(colBase + R0) * D_DIM + sg * 8;

  // fragment read bases: byte = R*64 + (quad ^ ((R>>1)&3))*16
  const int laneOff = ((quad ^ ((m16 >> 1) & 3)) << 4) + m16 * 64;
  const int aOff = wm * 8192 + laneOff;
  const int bOff = wn * 4096 + laneOff;

  float csq[4];
#pragma unroll
  for (int j = 0; j < 4; ++j) csq[j] = sq[colBase + wn * 64 + j * 16 + m16];

  f32x4 acc[8][4];
  const f32x4 zero = {0.0f, 0.0f, 0.0f, 0.0f};
#pragma unroll
  for (int i = 0; i < 8; ++i)
#pragma unroll
    for (int j = 0; j < 4; ++j) acc[i][j] = zero;

#define STAGE(P, EOFF, REGION)                                         \
  {                                                                    \
    gl_lds16((P) + (EOFF), smem + (REGION) + t * 16);                  \
    gl_lds16((P) + (EOFF) + 98304, smem + (REGION) + 8192 + t * 16);   \
  }

  short8 aF[4], bF[4];
#define LDA(BASE)                                                            \
  {                                                                          \
    _Pragma("unroll") for (int ii = 0; ii < 4; ++ii)                         \
        aF[ii] = *(const short8*)(smem + (BASE) + ii * 1024 + aOff);         \
  }
#define LDB(BASE)                                                            \
  {                                                                          \
    _Pragma("unroll") for (int j = 0; j < 4; ++j)                            \
        bF[j] = *(const short8*)(smem + (BASE) + j * 1024 + bOff);           \
  }
#define MFMAH(MH)                                                            \
  {                                                                          \
    __builtin_amdgcn_s_setprio(1);                                           \
    _Pragma("unroll") for (int ii = 0; ii < 4; ++ii)                         \
        _Pragma("unroll") for (int j = 0; j < 4; ++j)                        \
            acc[(MH) * 4 + ii][j] =                                          \
                __builtin_amdgcn_mfma_f32_16x16x32_bf16(                     \
                    aF[ii], bF[j], acc[(MH) * 4 + ii][j], 0, 0, 0);          \
    __builtin_amdgcn_s_setprio(0);                                           \
  }

// phases: P1=(M0,kh0) reads A0+B0, stages A'(kh0); P2=(M1,kh0) reads A0hi, stages
// B'(kh0), vmcnt; P3=(M0,kh1) reads A1+B1, stages A'(kh1); P4=(M1,kh1), vmcnt.
#define PH1(B, KT, S)                                                \
  {                                                                  \
    LDA(AREG(B, 0));                                                 \
    LDB(BREG(B, 0));                                                 \
    if (S) STAGE(pA, ((KT) + 1) * 64, AREG((B) ^ 1, 0));             \
    BAR();                                                           \
    LGKM0();                                                         \
    MFMAH(0);                                                        \
    BAR();                                                           \
  }
#define PH2(B, KT, S, VMWX)                                          \
  {                                                                  \
    LDA(AREG(B, 0) + 4096);                                          \
    if (S) STAGE(pB, ((KT) + 1) * 64, BREG((B) ^ 1, 0));             \
    VMWX;                                                            \
    BAR();                                                           \
    LGKM0();                                                         \
    MFMAH(1);                                                        \
    BAR();                                                           \
  }
#define PH3(B, KT, S)                                                \
  {                                                                  \
    LDA(AREG(B, 1));                                                 \
    LDB(BREG(B, 1));                                                 \
    if (S) STAGE(pA, ((KT) + 1) * 64 + 32, AREG((B) ^ 1, 1));        \
    BAR();                                                           \
    LGKM0();                                                         \
    MFMAH(0);                                                        \
    BAR();                                                           \
  }
#define PH4(B, KT, S, VMWX)                                          \
  {                                                                  \
    LDA(AREG(B, 1) + 4096);                                          \
    if (S) STAGE(pB, ((KT) + 1) * 64 + 32, BREG((B) ^ 1, 1));        \
    VMWX;                                                            \
    BAR();                                                           \
    LGKM0();                                                         \
    MFMAH(1);                                                        \
    BAR();                                                           \
  }
#define KTILE4(B, KT, S, VA, VB) \
  {                              \
    PH1(B, KT, S);               \
    PH2(B, KT, S, VA);           \
    PH3(B, KT, S);               \
    PH4(B, KT, S, VB);           \
  }

  // prologue: stage tile 0's 4 units (8 loads); need first 2 units before P1 reads
  STAGE(pA, 0, AREG(0, 0));
  STAGE(pB, 0, BREG(0, 0));
  STAGE(pA, 32, AREG(0, 1));
  STAGE(pB, 32, BREG(0, 1));
  VMW(4);
  BAR();

  for (int kt = 0; kt < 10; kt += 2) {
    KTILE4(0, kt, 1, VMW(4), VMW(4));
    KTILE4(1, kt + 1, 1, VMW(4), VMW(4));
  }
  KTILE4(0, 10, 1, VMW(4), VMW(4));
  KTILE4(1, 11, 0, VMW(0), (void)0);

  // ---------------- epilogue: 4 groups of 64 rows ----------------
  // selection key = csq[col] - 2*G (row-constant rsq added after: order-invariant)
  float* distS = (float*)smem;  // [64][260] f32, reuses staging LDS
#pragma unroll
  for (int g = 0; g < 4; ++g) {
    BAR();
    if (wm == (g >> 1)) {
      const int ih = (g & 1) * 4;
#pragma unroll
      for (int ii = 0; ii < 4; ++ii)
#pragma unroll
        for (int j = 0; j < 4; ++j)
#pragma unroll
          for (int r = 0; r < 4; ++r)
            distS[(ii * 16 + quad * 4 + r) * 260 + wn * 64 + j * 16 + m16] =
                csq[j] - 2.0f * acc[ih + ii][j][r];
    }
    BAR();
    // select: 8 threads/row x 32 cols, per-seg rotated start
    const int r_l = t >> 3, s = t & 7;
    const float* drow = distS + r_l * 260 + s * 32;
    float v[6];
#pragma unroll
    for (int q = 0; q < 6; ++q) v[q] = 1e30f;
#pragma unroll
    for (int k = 0; k < 8; ++k) {
      f32x4 dv = *(const f32x4*)(drow + ((k + s) & 7) * 4);
      ins6(dv[0], v);
      ins6(dv[1], v);
      ins6(dv[2], v);
      ins6(dv[3], v);
    }
    // in-wave butterfly merge across the 8 segment-threads of each row
#pragma unroll
    for (int st = 1; st <= 4; st <<= 1) {
      float o[6];
#pragma unroll
      for (int q = 0; q < 6; ++q) o[q] = __shfl_xor(v[q], st, 64);
#pragma unroll
      for (int q = 0; q < 6; ++q) ins6(o[q], v);
    }
    if (s == 0) {
      const int grow = rowBase + g * 64 + r_l;
      const float rsq = sq[grow];
      float* o = cand + ((size_t)grow * NCHUNK + chunk) * 8;
      f32x4 w0 = {fmaxf(v[0] + rsq, 0.0f), fmaxf(v[1] + rsq, 0.0f),
                  fmaxf(v[2] + rsq, 0.0f), fmaxf(v[3] + rsq, 0.0f)};
      f32x4 w1 = {fmaxf(v[4] + rsq, 0.0f), fmaxf(v[5] + rsq, 0.0f), 1e30f, 1e30f};
      *(f32x4*)o = w0;
      *(f32x4*)(o + 4) = w1;
    }
  }
}

// kernel 3: per-row merge of chunk candidates (d^2) -> sqrt -> log -> global sum.
// 8 lanes per row, contiguous 32B reads, butterfly merge.
__global__ __launch_bounds__(256) void knn_merge_kernel(
    const float* __restrict__ cand, float* __restrict__ acc) {
  const int t = threadIdx.x;
  const int r = blockIdx.x * 32 + (t >> 3);
  const float* cr = cand + (size_t)r * (NCHUNK * 8) + (size_t)(t & 7) * 32;
  float v[6];
#pragma unroll
  for (int s = 0; s < 6; ++s) v[s] = 1e30f;
#pragma unroll
  for (int c = 0; c < 4; ++c) {
    f32x4 d0 = *(const f32x4*)(cr + c * 8);
    f32x4 d1 = *(const f32x4*)(cr + c * 8 + 4);
    ins6(d0[0], v);
    ins6(d0[1], v);
    ins6(d0[2], v);
    ins6(d0[3], v);
    ins6(d1[0], v);
    ins6(d1[1], v);
  }
#pragma unroll
  for (int st = 1; st <= 4; st <<= 1) {
    float o[6];
#pragma unroll
    for (int q = 0; q < 6; ++q) o[q] = __shfl_xor(v[q], st, 64);
#pragma unroll
    for (int q = 0; q < 6; ++q) ins6(o[q], v);
  }
  float term = 0.0f;
  if ((t & 7) == 0) {
    // v sorted ascending on d^2: v[0] = self (~0); knn_mean = mean of sqrt(v[1..5])
    const float mean =
        (sqrtf(v[1]) + sqrtf(v[2]) + sqrtf(v[3]) + sqrtf(v[4]) + sqrtf(v[5])) * 0.2f;
    term = logf(mean + 1e-8f);
  }
#pragma unroll
  for (int off = 32; off > 0; off >>= 1) term += __shfl_down(term, off, 64);
  __shared__ float red[4];
  if ((t & 63) == 0) red[t >> 6] = term;
  __syncthreads();
  if (t == 0) atomicAdd(acc, red[0] + red[1] + red[2] + red[3]);
}

__global__ void finalize_kernel(const float* __restrict__ acc, float* __restrict__ out) {
  out[0] = -acc[0] * (1.0f / 8192.0f);
}

extern "C" void kernel_launch(void* const* d_in, const int* in_sizes, int n_in,
                              void* d_out, int out_size, void* d_ws, size_t ws_size,
                              hipStream_t stream) {
  const float* x = (const float*)d_in[0];
  float* out = (float*)d_out;
  char* ws = (char*)d_ws;
  unsigned short* xb = (unsigned short*)(ws + WS_XB);
  float* sq = (float*)(ws + WS_SQ);
  float* cand = (float*)(ws + WS_CAND);
  float* acc = (float*)(ws + WS_ACC);

  cast_sq_kernel<<<B_DIM / 4, 256, 0, stream>>>(x, xb, sq, acc);
  knn_gemm_kernel<<<dim3(B_DIM / BM, B_DIM / BN), 512, 0, stream>>>(xb, sq, cand);
  knn_merge_kernel<<<B_DIM / 32, 256, 0, stream>>>(cand, acc);
  finalize_kernel<<<1, 1, 0, stream>>>(acc, out);
}

// Round 3
// 163.088 us; speedup vs baseline: 1.7599x; 1.2631x over previous
//
#include <hip/hip_runtime.h>
#include <hip/hip_bf16.h>

#define D_DIM 768
#define B_DIM 8192
#define NT 64           // tile grid dim (8192/128)
#define NTILES 2080     // NT*(NT+1)/2 upper-triangle tiles
#define BM 128
#define BN 128

typedef __attribute__((ext_vector_type(8))) short short8;
typedef __attribute__((ext_vector_type(4))) float f32x4;
typedef __attribute__((ext_vector_type(2))) float f32x2;
typedef __attribute__((ext_vector_type(4))) unsigned short ushort4v;

// ws layout (bytes)
#define WS_XB   0                               // bf16[8192*768]   = 12,582,912
#define WS_SQ   12582912                        // float[8192]      = 32,768
#define WS_CAND 12615680                        // float[8192*64*6] = 12,582,912
#define WS_ACC  25198592                        // float[1]

__device__ __forceinline__ void gl_lds16(const void* g, void* lds) {
  __builtin_amdgcn_global_load_lds(
      (const __attribute__((address_space(1))) unsigned int*)g,
      (__attribute__((address_space(3))) unsigned int*)lds, 16, 0, 0);
}

// branchless: maintain v[0..5] = six smallest seen, sorted ascending.
__device__ __forceinline__ void ins6(float c, float* v) {
  v[5] = fminf(v[5], c);
#pragma unroll
  for (int s = 5; s > 0; --s) {
    float lo = fminf(v[s - 1], v[s]);
    float hi = fmaxf(v[s - 1], v[s]);
    v[s - 1] = lo;
    v[s] = hi;
  }
}

// kernel 1: cast fp32 -> bf16 (vectorized), row sum-of-squares of bf16 values.
__global__ __launch_bounds__(256) void cast_sq_kernel(
    const float* __restrict__ x, unsigned short* __restrict__ xb,
    float* __restrict__ sq, float* __restrict__ acc) {
  const int t = threadIdx.x;
  const int w = t >> 6, lane = t & 63;
  const int row = blockIdx.x * 4 + w;
  if (blockIdx.x == 0 && t == 0) acc[0] = 0.0f;
  const f32x4* xr = (const f32x4*)(x + (size_t)row * D_DIM);
  ushort4v* xbr = (ushort4v*)(xb + (size_t)row * D_DIM);
  float s = 0.0f;
#pragma unroll
  for (int c = 0; c < 3; ++c) {
    const int idx = c * 64 + lane;
    f32x4 v = xr[idx];
    ushort4v u;
#pragma unroll
    for (int e = 0; e < 4; ++e) {
      __hip_bfloat16 h = __float2bfloat16(v[e]);
      unsigned short us;
      __builtin_memcpy(&us, &h, 2);
      u[e] = us;
      float vb = __bfloat162float(h);
      s += vb * vb;
    }
    xbr[idx] = u;
  }
#pragma unroll
  for (int off = 32; off > 0; off >>= 1) s += __shfl_down(s, off, 64);
  if (lane == 0) sq[row] = s;
}

// ---------------- kernel 2: symmetric 128x128 tiles, 2 blocks/CU TLP ----------------
// Upper-triangle tile (rt,ct): row-wise top-6 -> cand[row][ct]; for rt<ct also
// column-wise top-6 -> cand[col][rt] (same Gram values, d symmetric). 2x less GEMM.
// 4 waves (2x2), wave tile 64x64. LDS 64 KiB -> 2 independent blocks/CU: when one
// block's waves wait on LDS reads, the other's feed the MFMA pipe (no cross-block
// barriers). Counted vmcnt(4), 2-section-deep prefetch, never drained mid-loop.
#define AREGn(b, kh) ((b) * 32768 + (kh) * 8192)
#define BREGn(b, kh) ((b) * 32768 + 16384 + (kh) * 8192)
#define VMW(N) asm volatile("s_waitcnt vmcnt(" #N ")" ::: "memory")
#define BAR()                         \
  {                                   \
    asm volatile("" ::: "memory");    \
    __builtin_amdgcn_s_barrier();     \
    asm volatile("" ::: "memory");    \
  }
#define TRI(x) ((x) * NT - (x) * ((x) - 1) / 2)

__global__ __launch_bounds__(256, 2) void knn_gemm_kernel(
    const unsigned short* __restrict__ xb, const float* __restrict__ sq,
    float* __restrict__ cand) {
  __shared__ __align__(16) char smem[65536];
  const int t = threadIdx.x;
  const int lane = t & 63, w = t >> 6;
  const int wm = w >> 1, wn = w & 1;  // 2x2 wave grid; wave tile 64x64
  const int quad = lane >> 4, m16 = lane & 15;

  // XCD chunking (2080 % 8 == 0) + triangle decode
  const int wg = (blockIdx.x & 7) * (NTILES / 8) + (blockIdx.x >> 3);
  int i0 = (int)(64.5f - sqrtf(64.5f * 64.5f - 2.0f * (float)wg));
  i0 = max(0, min(NT - 1, i0));
  while (TRI(i0 + 1) <= wg) ++i0;
  while (TRI(i0) > wg) --i0;
  const int rt = i0, ct = i0 + (wg - TRI(i0));
  const bool offdiag = (ct > rt);
  const int rowBase = rt * BM, colBase = ct * BN;

  // staging: thread t -> LDS row R0=t>>2 (and R0+64), lds seg t&3.
  // swizzle: lds slot (R, s) holds global seg s ^ ((R>>1)&3)  (same sg for R0+64)
  const int R0 = t >> 2;
  const int sg = (t & 3) ^ ((t >> 3) & 3);
  const unsigned short* pA = xb + (size_t)(rowBase + R0) * D_DIM + sg * 8;
  const unsigned short* pB = xb + (size_t)(colBase + R0) * D_DIM + sg * 8;

  // fragment read: byte = R*64 + (quad ^ ((R>>1)&3))*16; (R>>1)&3 == (m16>>1)&3
  const int laneOff = ((quad ^ ((m16 >> 1) & 3)) << 4) + m16 * 64;
  const int aOff = wm * 4096 + laneOff;
  const int bOff = wn * 4096 + laneOff;

  float rsq[16];
#pragma unroll
  for (int i = 0; i < 4; ++i)
#pragma unroll
    for (int r = 0; r < 4; ++r)
      rsq[i * 4 + r] = sq[rowBase + wm * 64 + i * 16 + quad * 4 + r];
  float csq[4];
#pragma unroll
  for (int j = 0; j < 4; ++j) csq[j] = sq[colBase + wn * 64 + j * 16 + m16];

  f32x4 acc[4][4];
  const f32x4 zero = {0.0f, 0.0f, 0.0f, 0.0f};
#pragma unroll
  for (int i = 0; i < 4; ++i)
#pragma unroll
    for (int j = 0; j < 4; ++j) acc[i][j] = zero;

#define STAGE(P, EOFF, REGION)                                           \
  {                                                                      \
    gl_lds16((P) + (EOFF), smem + (REGION) + t * 16);                    \
    gl_lds16((P) + (EOFF) + 64 * D_DIM, smem + (REGION) + 4096 + t * 16); \
  }

  short8 aF[4], bF[4];
#define LDA(BASE)                                                            \
  {                                                                          \
    _Pragma("unroll") for (int ii = 0; ii < 4; ++ii)                         \
        aF[ii] = *(const short8*)(smem + (BASE) + ii * 1024 + aOff);         \
  }
#define LDB(BASE)                                                            \
  {                                                                          \
    _Pragma("unroll") for (int j = 0; j < 4; ++j)                            \
        bF[j] = *(const short8*)(smem + (BASE) + j * 1024 + bOff);           \
  }
#define MFMA16                                                               \
  {                                                                          \
    __builtin_amdgcn_s_setprio(1);                                           \
    _Pragma("unroll") for (int ii = 0; ii < 4; ++ii)                         \
        _Pragma("unroll") for (int j = 0; j < 4; ++j)                        \
            acc[ii][j] = __builtin_amdgcn_mfma_f32_16x16x32_bf16(            \
                aF[ii], bF[j], acc[ii][j], 0, 0, 0);                         \
    __builtin_amdgcn_s_setprio(0);                                           \
  }

// section (tile KT, K-half KH, buffer B): certify own regions (vmcnt+bar),
// prefetch tile KT+1's same-KH regions into B^1, read frags, 16 MFMA.
#define SEC(B, KH, KT, S, VMWX)                                        \
  {                                                                    \
    VMWX;                                                              \
    BAR();                                                             \
    if (S) {                                                           \
      STAGE(pA, ((KT) + 1) * 64 + (KH) * 32, AREGn((B) ^ 1, KH));      \
      STAGE(pB, ((KT) + 1) * 64 + (KH) * 32, BREGn((B) ^ 1, KH));      \
    }                                                                  \
    LDA(AREGn(B, KH));                                                 \
    LDB(BREGn(B, KH));                                                 \
    MFMA16;                                                            \
  }

  // prologue: stage tile 0 (8 loads; vmcnt(4) in first section waits kh0's 4)
  STAGE(pA, 0, AREGn(0, 0));
  STAGE(pB, 0, BREGn(0, 0));
  STAGE(pA, 32, AREGn(0, 1));
  STAGE(pB, 32, BREGn(0, 1));

  for (int kt = 0; kt < 11; ++kt) {
    const int b = kt & 1;
    SEC(b, 0, kt, 1, VMW(4));
    SEC(b, 1, kt, 1, VMW(4));
  }
  SEC(1, 0, 11, 0, VMW(4));
  SEC(1, 1, 11, 0, VMW(0));

  // ---------------- epilogue: 2 groups of 64 rows ----------------
  float* distS = (float*)smem;                 // [64][132] f32
  float* rsqS = (float*)(smem + 34816);        // [64] f32
  float colrun[6];
#pragma unroll
  for (int q = 0; q < 6; ++q) colrun[q] = 1e30f;

#pragma unroll
  for (int g = 0; g < 2; ++g) {
    BAR();
    if (wm == g) {
      // row-key = csq[col] - 2G (row-constant rsq added at write; order-invariant)
#pragma unroll
      for (int ii = 0; ii < 4; ++ii)
#pragma unroll
        for (int j = 0; j < 4; ++j)
#pragma unroll
          for (int r = 0; r < 4; ++r)
            distS[(ii * 16 + quad * 4 + r) * 132 + wn * 64 + j * 16 + m16] =
                csq[j] - 2.0f * acc[ii][j][r];
      if (wn == 0 && m16 == 0) {
#pragma unroll
        for (int ii = 0; ii < 4; ++ii)
#pragma unroll
          for (int r = 0; r < 4; ++r)
            rsqS[ii * 16 + quad * 4 + r] = rsq[ii * 4 + r];
      }
    }
    BAR();
    // row select: 4 threads/row x 32 cols, rotated start (bank-friendly)
    const int row_l = t >> 2, seg = t & 3;
    const float* drow = distS + row_l * 132 + seg * 32;
    float v[6];
#pragma unroll
    for (int q = 0; q < 6; ++q) v[q] = 1e30f;
#pragma unroll
    for (int k = 0; k < 8; ++k) {
      f32x4 dv = *(const f32x4*)(drow + ((k + seg) & 7) * 4);
      ins6(dv[0], v);
      ins6(dv[1], v);
      ins6(dv[2], v);
      ins6(dv[3], v);
    }
#pragma unroll
    for (int st = 1; st <= 2; st <<= 1) {
      float o[6];
#pragma unroll
      for (int q = 0; q < 6; ++q) o[q] = __shfl_xor(v[q], st, 64);
#pragma unroll
      for (int q = 0; q < 6; ++q) ins6(o[q], v);
    }
    if (seg == 0) {
      const int grow = rowBase + g * 64 + row_l;
      const float rq = rsqS[row_l];
      float* o = cand + (size_t)(grow * NT + ct) * 6;
      f32x2 w0 = {fmaxf(v[0] + rq, 0.0f), fmaxf(v[1] + rq, 0.0f)};
      f32x2 w1 = {fmaxf(v[2] + rq, 0.0f), fmaxf(v[3] + rq, 0.0f)};
      f32x2 w2 = {fmaxf(v[4] + rq, 0.0f), fmaxf(v[5] + rq, 0.0f)};
      *(f32x2*)o = w0;
      *(f32x2*)(o + 2) = w1;
      *(f32x2*)(o + 4) = w2;
    }
    // column partial (off-diagonal only): key = distS + rsq[row] = full d^2
    if (offdiag) {
      const int col = t >> 1, h = t & 1;
#pragma unroll
      for (int k = 0; k < 32; ++k) {
        const int r = h * 32 + k;
        ins6(distS[r * 132 + col] + rsqS[r], colrun);
      }
    }
  }
  if (offdiag) {
    float o2[6];
#pragma unroll
    for (int q = 0; q < 6; ++q) o2[q] = __shfl_xor(colrun[q], 1, 64);
#pragma unroll
    for (int q = 0; q < 6; ++q) ins6(o2[q], colrun);
    if ((t & 1) == 0) {
      const int colg = colBase + (t >> 1);
      float* o = cand + (size_t)(colg * NT + rt) * 6;
      f32x2 w0 = {fmaxf(colrun[0], 0.0f), fmaxf(colrun[1], 0.0f)};
      f32x2 w1 = {fmaxf(colrun[2], 0.0f), fmaxf(colrun[3], 0.0f)};
      f32x2 w2 = {fmaxf(colrun[4], 0.0f), fmaxf(colrun[5], 0.0f)};
      *(f32x2*)o = w0;
      *(f32x2*)(o + 2) = w1;
      *(f32x2*)(o + 4) = w2;
    }
  }
}

// kernel 3: per-row merge of 64 chunk-candidates (d^2) -> sqrt -> log -> global sum.
// 8 lanes/row, 192 contiguous bytes each, butterfly merge.
__global__ __launch_bounds__(256) void knn_merge_kernel(
    const float* __restrict__ cand, float* __restrict__ acc) {
  const int t = threadIdx.x;
  const int r = blockIdx.x * 32 + (t >> 3);
  const float* cr = cand + (size_t)r * (NT * 6) + (size_t)(t & 7) * 48;
  float v[6];
#pragma unroll
  for (int s = 0; s < 6; ++s) v[s] = 1e30f;
#pragma unroll
  for (int c = 0; c < 12; ++c) {
    f32x4 dv = *(const f32x4*)(cr + c * 4);
    ins6(dv[0], v);
    ins6(dv[1], v);
    ins6(dv[2], v);
    ins6(dv[3], v);
  }
#pragma unroll
  for (int st = 1; st <= 4; st <<= 1) {
    float o[6];
#pragma unroll
    for (int q = 0; q < 6; ++q) o[q] = __shfl_xor(v[q], st, 64);
#pragma unroll
    for (int q = 0; q < 6; ++q) ins6(o[q], v);
  }
  float term = 0.0f;
  if ((t & 7) == 0) {
    // v sorted ascending on d^2: v[0] = self (0); knn_mean = mean of sqrt(v[1..5])
    const float mean =
        (sqrtf(v[1]) + sqrtf(v[2]) + sqrtf(v[3]) + sqrtf(v[4]) + sqrtf(v[5])) * 0.2f;
    term = logf(mean + 1e-8f);
  }
#pragma unroll
  for (int off = 32; off > 0; off >>= 1) term += __shfl_down(term, off, 64);
  __shared__ float red[4];
  if ((t & 63) == 0) red[t >> 6] = term;
  __syncthreads();
  if (t == 0) atomicAdd(acc, red[0] + red[1] + red[2] + red[3]);
}

__global__ void finalize_kernel(const float* __restrict__ acc, float* __restrict__ out) {
  out[0] = -acc[0] * (1.0f / 8192.0f);
}

extern "C" void kernel_launch(void* const* d_in, const int* in_sizes, int n_in,
                              void* d_out, int out_size, void* d_ws, size_t ws_size,
                              hipStream_t stream) {
  const float* x = (const float*)d_in[0];
  float* out = (float*)d_out;
  char* ws = (char*)d_ws;
  unsigned short* xb = (unsigned short*)(ws + WS_XB);
  float* sq = (float*)(ws + WS_SQ);
  float* cand = (float*)(ws + WS_CAND);
  float* acc = (float*)(ws + WS_ACC);

  cast_sq_kernel<<<B_DIM / 4, 256, 0, stream>>>(x, xb, sq, acc);
  knn_gemm_kernel<<<NTILES, 256, 0, stream>>>(xb, sq, cand);
  knn_merge_kernel<<<B_DIM / 32, 256, 0, stream>>>(cand, acc);
  finalize_kernel<<<1, 1, 0, stream>>>(acc, out);
}

// Round 4
// 161.390 us; speedup vs baseline: 1.7784x; 1.0105x over previous
//
#include <hip/hip_runtime.h>
#include <hip/hip_bf16.h>

#define D_DIM 768
#define B_DIM 8192
#define NT 64           // tile grid dim (8192/128)
#define NTILES 2080     // NT*(NT+1)/2 upper-triangle tiles
#define BM 128
#define BN 128

typedef __attribute__((ext_vector_type(8))) short short8;
typedef __attribute__((ext_vector_type(4))) float f32x4;
typedef __attribute__((ext_vector_type(2))) float f32x2;
typedef __attribute__((ext_vector_type(4))) unsigned short ushort4v;

// ws layout (bytes)
#define WS_XB   0                               // bf16[8192*768]   = 12,582,912
#define WS_SQ   12582912                        // float[8192]      = 32,768
#define WS_CAND 12615680                        // float[8192*64*6] = 12,582,912
#define WS_ACC  25198592                        // float[1]
#define WS_TKT  25198596                        // uint[1]

__device__ __forceinline__ void gl_lds16(const void* g, void* lds) {
  __builtin_amdgcn_global_load_lds(
      (const __attribute__((address_space(1))) unsigned int*)g,
      (__attribute__((address_space(3))) unsigned int*)lds, 16, 0, 0);
}

// branchless: maintain v[0..5] = six smallest seen, sorted ascending.
__device__ __forceinline__ void ins6(float c, float* v) {
  v[5] = fminf(v[5], c);
#pragma unroll
  for (int s = 5; s > 0; --s) {
    float lo = fminf(v[s - 1], v[s]);
    float hi = fmaxf(v[s - 1], v[s]);
    v[s - 1] = lo;
    v[s] = hi;
  }
}

// kernel 1: cast fp32 -> bf16 (vectorized), row sum-of-squares of bf16 values.
__global__ __launch_bounds__(256) void cast_sq_kernel(
    const float* __restrict__ x, unsigned short* __restrict__ xb,
    float* __restrict__ sq, float* __restrict__ acc,
    unsigned int* __restrict__ tkt) {
  const int t = threadIdx.x;
  const int w = t >> 6, lane = t & 63;
  const int row = blockIdx.x * 4 + w;
  if (blockIdx.x == 0 && t == 0) {
    acc[0] = 0.0f;
    tkt[0] = 0u;
  }
  const f32x4* xr = (const f32x4*)(x + (size_t)row * D_DIM);
  ushort4v* xbr = (ushort4v*)(xb + (size_t)row * D_DIM);
  float s = 0.0f;
#pragma unroll
  for (int c = 0; c < 3; ++c) {
    const int idx = c * 64 + lane;
    f32x4 v = xr[idx];
    ushort4v u;
#pragma unroll
    for (int e = 0; e < 4; ++e) {
      __hip_bfloat16 h = __float2bfloat16(v[e]);
      unsigned short us;
      __builtin_memcpy(&us, &h, 2);
      u[e] = us;
      float vb = __bfloat162float(h);
      s += vb * vb;
    }
    xbr[idx] = u;
  }
#pragma unroll
  for (int off = 32; off > 0; off >>= 1) s += __shfl_down(s, off, 64);
  if (lane == 0) sq[row] = s;
}

// ------- kernel 2: symmetric 128x128 tiles, ring-of-5 pipeline, 2 blocks/CU -------
// 24 sections (12 K-tiles x 2 K-halves); section s consumes ring slot s%5 and
// prefetches section s+4 into slot (s+4)%5 (freed at s-1; safe after the barrier).
// Steady vmcnt(12) = 16 loads in flight (2 K-tiles deep); drains 12/8/4/0 only at
// the tail. 80 KiB LDS -> still 2 independent blocks/CU for TLP overlap.
// Tile order: 16x16-tile band-blocks, rt-major inside (working set ~3.3 MB < L2);
// XCD k gets 260 consecutive tiles of this order.
#define AS(slot) ((slot) * 8192)
#define BS(slot) (40960 + (slot) * 8192)
#define VMW(N) asm volatile("s_waitcnt vmcnt(" #N ")" ::: "memory")
#define BAR()                         \
  {                                   \
    asm volatile("" ::: "memory");    \
    __builtin_amdgcn_s_barrier();     \
    asm volatile("" ::: "memory");    \
  }

__global__ __launch_bounds__(256, 2) void knn_gemm_kernel(
    const unsigned short* __restrict__ xb, const float* __restrict__ sq,
    float* __restrict__ cand) {
  __shared__ __align__(16) char smem[81920];
  const int t = threadIdx.x;
  const int lane = t & 63, w = t >> 6;
  const int wm = w >> 1, wn = w & 1;  // 2x2 wave grid; wave tile 64x64
  const int quad = lane >> 4, m16 = lane & 15;

  // band-blocked triangle order, XCD-chunked (2080 = 8*260, bijective)
  const int g = (blockIdx.x & 7) * (NTILES / 8) + (blockIdx.x >> 3);
  int rt = 0, ct = 0;
  {
    int base = 0, found = 0;
    for (int s = 0; s < 4; ++s) {
      for (int cb = s; cb < 4; ++cb) {
        const int sz = (cb == s) ? 136 : 256;
        if (!found && g < base + sz) {
          int loc = g - base;
          if (cb == s) {  // triangular 16x16 block, row-major, c>=r
            int r = 0;
            while (loc >= 16 - r) {
              loc -= 16 - r;
              ++r;
            }
            rt = s * 16 + r;
            ct = cb * 16 + r + loc;
          } else {  // full 16x16 block, rt-major raster
            rt = s * 16 + (loc >> 4);
            ct = cb * 16 + (loc & 15);
          }
          found = 1;
        }
        base += sz;
      }
    }
  }
  const bool offdiag = (ct > rt);
  const int rowBase = rt * BM, colBase = ct * BN;

  // staging: thread t -> LDS row R0=t>>2 (and R0+64), lds seg t&3.
  // swizzle: lds slot (R, s) holds global seg s ^ ((R>>1)&3)
  const int R0 = t >> 2;
  const int sg = (t & 3) ^ ((t >> 3) & 3);
  const unsigned short* pA = xb + (size_t)(rowBase + R0) * D_DIM + sg * 8;
  const unsigned short* pB = xb + (size_t)(colBase + R0) * D_DIM + sg * 8;

  // fragment read: byte = R*64 + (quad ^ ((R>>1)&3))*16; (R>>1)&3 == (m16>>1)&3
  const int laneOff = ((quad ^ ((m16 >> 1) & 3)) << 4) + m16 * 64;
  const int aOff = wm * 4096 + laneOff;
  const int bOff = wn * 4096 + laneOff;

  float rsq[16];
#pragma unroll
  for (int i = 0; i < 4; ++i)
#pragma unroll
    for (int r = 0; r < 4; ++r)
      rsq[i * 4 + r] = sq[rowBase + wm * 64 + i * 16 + quad * 4 + r];
  float csq[4];
#pragma unroll
  for (int j = 0; j < 4; ++j) csq[j] = sq[colBase + wn * 64 + j * 16 + m16];

  f32x4 acc[4][4];
  const f32x4 zero = {0.0f, 0.0f, 0.0f, 0.0f};
#pragma unroll
  for (int i = 0; i < 4; ++i)
#pragma unroll
    for (int j = 0; j < 4; ++j) acc[i][j] = zero;

#define STAGE(P, EOFF, REGION)                                            \
  {                                                                       \
    gl_lds16((P) + (EOFF), smem + (REGION) + t * 16);                     \
    gl_lds16((P) + (EOFF) + 64 * D_DIM, smem + (REGION) + 4096 + t * 16); \
  }

  short8 aF[4], bF[4];
#define LDA(BASE)                                                            \
  {                                                                          \
    _Pragma("unroll") for (int ii = 0; ii < 4; ++ii)                         \
        aF[ii] = *(const short8*)(smem + (BASE) + ii * 1024 + aOff);         \
  }
#define LDB(BASE)                                                            \
  {                                                                          \
    _Pragma("unroll") for (int j = 0; j < 4; ++j)                            \
        bF[j] = *(const short8*)(smem + (BASE) + j * 1024 + bOff);           \
  }
#define MFMA16                                                               \
  {                                                                          \
    __builtin_amdgcn_s_setprio(1);                                           \
    _Pragma("unroll") for (int ii = 0; ii < 4; ++ii)                         \
        _Pragma("unroll") for (int j = 0; j < 4; ++j)                        \
            acc[ii][j] = __builtin_amdgcn_mfma_f32_16x16x32_bf16(            \
                aF[ii], bF[j], acc[ii][j], 0, 0, 0);                         \
    __builtin_amdgcn_s_setprio(0);                                           \
  }

  // prologue: sections 0..3 -> slots 0..3 (16 loads in flight)
  STAGE(pA, 0, AS(0));
  STAGE(pB, 0, BS(0));
  STAGE(pA, 32, AS(1));
  STAGE(pB, 32, BS(1));
  STAGE(pA, 64, AS(2));
  STAGE(pB, 64, BS(2));
  STAGE(pA, 96, AS(3));
  STAGE(pB, 96, BS(3));

  // steady: sections 0..19 (section s at element offset s*32)
  for (int sb = 0; sb < 4; ++sb) {
    const int s0 = sb * 5;
#pragma unroll
    for (int i = 0; i < 5; ++i) {
      const int pre = (i + 4) % 5;
      VMW(12);
      BAR();
      STAGE(pA, (s0 + i + 4) * 32, AS(pre));
      STAGE(pB, (s0 + i + 4) * 32, BS(pre));
      LDA(AS(i));
      LDB(BS(i));
      MFMA16;
    }
  }
  // tail: sections 20..23 in slots 0..3, counted drain
  VMW(12);
  BAR();
  LDA(AS(0));
  LDB(BS(0));
  MFMA16;
  VMW(8);
  BAR();
  LDA(AS(1));
  LDB(BS(1));
  MFMA16;
  VMW(4);
  BAR();
  LDA(AS(2));
  LDB(BS(2));
  MFMA16;
  VMW(0);
  BAR();
  LDA(AS(3));
  LDB(BS(3));
  MFMA16;

  // ---------------- epilogue: 2 groups of 64 rows ----------------
  float* distS = (float*)smem;                 // [64][132] f32
  float* rsqS = (float*)(smem + 34816);        // [64] f32
  float colrun[6];
#pragma unroll
  for (int q = 0; q < 6; ++q) colrun[q] = 1e30f;

#pragma unroll
  for (int gg = 0; gg < 2; ++gg) {
    BAR();
    if (wm == gg) {
      // row-key = csq[col] - 2G (row-constant rsq added at write; order-invariant)
#pragma unroll
      for (int ii = 0; ii < 4; ++ii)
#pragma unroll
        for (int j = 0; j < 4; ++j)
#pragma unroll
          for (int r = 0; r < 4; ++r)
            distS[(ii * 16 + quad * 4 + r) * 132 + wn * 64 + j * 16 + m16] =
                csq[j] - 2.0f * acc[ii][j][r];
      if (wn == 0 && m16 == 0) {
#pragma unroll
        for (int ii = 0; ii < 4; ++ii)
#pragma unroll
          for (int r = 0; r < 4; ++r)
            rsqS[ii * 16 + quad * 4 + r] = rsq[ii * 4 + r];
      }
    }
    BAR();
    // row select: 4 threads/row x 32 cols, rotated start (bank-friendly)
    const int row_l = t >> 2, seg = t & 3;
    const float* drow = distS + row_l * 132 + seg * 32;
    float v[6];
#pragma unroll
    for (int q = 0; q < 6; ++q) v[q] = 1e30f;
#pragma unroll
    for (int k = 0; k < 8; ++k) {
      f32x4 dv = *(const f32x4*)(drow + ((k + seg) & 7) * 4);
      ins6(dv[0], v);
      ins6(dv[1], v);
      ins6(dv[2], v);
      ins6(dv[3], v);
    }
#pragma unroll
    for (int st = 1; st <= 2; st <<= 1) {
      float o[6];
#pragma unroll
      for (int q = 0; q < 6; ++q) o[q] = __shfl_xor(v[q], st, 64);
#pragma unroll
      for (int q = 0; q < 6; ++q) ins6(o[q], v);
    }
    if (seg == 0) {
      const int grow = rowBase + gg * 64 + row_l;
      const float rq = rsqS[row_l];
      float* o = cand + (size_t)(grow * NT + ct) * 6;
      f32x2 w0 = {fmaxf(v[0] + rq, 0.0f), fmaxf(v[1] + rq, 0.0f)};
      f32x2 w1 = {fmaxf(v[2] + rq, 0.0f), fmaxf(v[3] + rq, 0.0f)};
      f32x2 w2 = {fmaxf(v[4] + rq, 0.0f), fmaxf(v[5] + rq, 0.0f)};
      *(f32x2*)o = w0;
      *(f32x2*)(o + 2) = w1;
      *(f32x2*)(o + 4) = w2;
    }
    // column partial (off-diagonal only): key = distS + rsq[row] = full d^2
    if (offdiag) {
      const int col = t >> 1, h = t & 1;
#pragma unroll
      for (int k = 0; k < 32; ++k) {
        const int r = h * 32 + k;
        ins6(distS[r * 132 + col] + rsqS[r], colrun);
      }
    }
  }
  if (offdiag) {
    float o2[6];
#pragma unroll
    for (int q = 0; q < 6; ++q) o2[q] = __shfl_xor(colrun[q], 1, 64);
#pragma unroll
    for (int q = 0; q < 6; ++q) ins6(o2[q], colrun);
    if ((t & 1) == 0) {
      const int colg = colBase + (t >> 1);
      float* o = cand + (size_t)(colg * NT + rt) * 6;
      f32x2 w0 = {fmaxf(colrun[0], 0.0f), fmaxf(colrun[1], 0.0f)};
      f32x2 w1 = {fmaxf(colrun[2], 0.0f), fmaxf(colrun[3], 0.0f)};
      f32x2 w2 = {fmaxf(colrun[4], 0.0f), fmaxf(colrun[5], 0.0f)};
      *(f32x2*)o = w0;
      *(f32x2*)(o + 2) = w1;
      *(f32x2*)(o + 4) = w2;
    }
  }
}

// kernel 3: per-row merge of 64 chunk-candidates -> sqrt -> log -> global sum,
// with fused finalize via ticket (last block writes the output).
__global__ __launch_bounds__(256) void knn_merge_kernel(
    const float* __restrict__ cand, float* __restrict__ acc,
    unsigned int* __restrict__ tkt, float* __restrict__ out) {
  const int t = threadIdx.x;
  const int r = blockIdx.x * 32 + (t >> 3);
  const float* cr = cand + (size_t)r * (NT * 6) + (size_t)(t & 7) * 48;
  float v[6];
#pragma unroll
  for (int s = 0; s < 6; ++s) v[s] = 1e30f;
#pragma unroll
  for (int c = 0; c < 12; ++c) {
    f32x4 dv = *(const f32x4*)(cr + c * 4);
    ins6(dv[0], v);
    ins6(dv[1], v);
    ins6(dv[2], v);
    ins6(dv[3], v);
  }
#pragma unroll
  for (int st = 1; st <= 4; st <<= 1) {
    float o[6];
#pragma unroll
    for (int q = 0; q < 6; ++q) o[q] = __shfl_xor(v[q], st, 64);
#pragma unroll
    for (int q = 0; q < 6; ++q) ins6(o[q], v);
  }
  float term = 0.0f;
  if ((t & 7) == 0) {
    // v sorted ascending on d^2: v[0] = self (0); knn_mean = mean of sqrt(v[1..5])
    const float mean =
        (sqrtf(v[1]) + sqrtf(v[2]) + sqrtf(v[3]) + sqrtf(v[4]) + sqrtf(v[5])) * 0.2f;
    term = logf(mean + 1e-8f);
  }
#pragma unroll
  for (int off = 32; off > 0; off >>= 1) term += __shfl_down(term, off, 64);
  __shared__ float red[4];
  if ((t & 63) == 0) red[t >> 6] = term;
  __syncthreads();
  if (t == 0) {
    atomicAdd(acc, red[0] + red[1] + red[2] + red[3]);
    __threadfence();
    const unsigned int tk = atomicAdd(tkt, 1u);
    if (tk == (B_DIM / 32) - 1) {
      const float total = atomicAdd(acc, 0.0f);  // coherent read of final sum
      out[0] = -total * (1.0f / 8192.0f);
    }
  }
}

extern "C" void kernel_launch(void* const* d_in, const int* in_sizes, int n_in,
                              void* d_out, int out_size, void* d_ws, size_t ws_size,
                              hipStream_t stream) {
  const float* x = (const float*)d_in[0];
  float* out = (float*)d_out;
  char* ws = (char*)d_ws;
  unsigned short* xb = (unsigned short*)(ws + WS_XB);
  float* sq = (float*)(ws + WS_SQ);
  float* cand = (float*)(ws + WS_CAND);
  float* acc = (float*)(ws + WS_ACC);
  unsigned int* tkt = (unsigned int*)(ws + WS_TKT);

  cast_sq_kernel<<<B_DIM / 4, 256, 0, stream>>>(x, xb, sq, acc, tkt);
  knn_gemm_kernel<<<NTILES, 256, 0, stream>>>(xb, sq, cand);
  knn_merge_kernel<<<B_DIM / 32, 256, 0, stream>>>(cand, acc, tkt, out);
}